// Round 13
// baseline (22131.799 us; speedup 1.0000x reference)
//
#include <hip/hip_runtime.h>
#include <math.h>

#define SCOPE __HIP_MEMORY_SCOPE_AGENT

constexpr int Bn = 64, Ln = 512, En = 128, Hn = 256, Tn = 512;
constexpr int NBLK = 512, NTHR = 256;     // 2 blocks/CU; 2-phase deferred-output schedule
constexpr int CTX_LD = 256, XPAD = 384, UPAD = 520;

// ---- LDS layout (floats) ----
constexpr int OFF_CTX = 0;                  // [64][256] ctx slice
constexpr int OFF_SCR = 64 * CTX_LD;        // 2048: u / x / PV partials / init stage
constexpr int OFF_INP = OFF_SCR + 2048;     // inp (own batch) [256]
constexpr int OFF_SS  = OFF_INP + 256;      // scores [64]
constexpr int OFF_ES  = OFF_SS + 64;        // e [64] (persists B_t -> A_{t+1})
constexpr int OFF_MK  = OFF_ES + 64;        // mask [64]
constexpr int OFF_VS  = OFF_MK + 64;        // V [256]
constexpr int OFF_GS  = OFF_VS + 256;       // gate pre-activations [2bb][64]
constexpr int OFF_ST  = OFF_GS + 128;       // stats [16][4]
constexpr int OFF_BA  = OFF_ST + 64;        // bain [256]
constexpr int OFF_HTL = OFF_BA + 256;       // own-slice h_t [2][16]
constexpr int OFF_BO  = OFF_HTL + 32;       // bo [256]
constexpr int OFF_HID = OFF_BO + 256;       // hidden (local, both batches) [2][256]
constexpr int SMEM_FL = OFF_HID + 512;      // 20384 floats = 81536 B -> 2 blocks/CU

// ---- output layout ----
constexpr size_t PTR_OFF = (size_t)Bn * Ln * Ln;
constexpr size_t HF_OFF  = PTR_OFF + (size_t)Bn * Ln;
constexpr size_t CF_OFF  = HF_OFF + (size_t)Bn * Hn;

// ---- ws: [0,64KB) flags (32 groups x 16 x 32 uints); then per-group floats ----
constexpr int GQ_HT    = 0;      // h_t [2 parity][2 bb][256]  (parity dbuf: 2-barrier gap)
constexpr int GQ_ATT   = 1024;   // att partials [2bb*8ck][256]
constexpr int GQ_STATS = 5120;   // [16][4] {S, candv, candi, pad}
constexpr int GQ_INPP  = 5184;   // inp partials [2bb][256g][16j]
constexpr int GQ_STRIDE = 5184 + 8192;   // 13376 floats/group

__device__ __forceinline__ float fast_tanh(float x) {
  const float e = __expf(2.0f * x);
  return 1.0f - __fdividef(2.0f, 1.0f + e);
}
__device__ __forceinline__ float sigmoidf_(float x) {
  return 1.0f / (1.0f + expf(-x));
}
__device__ __forceinline__ void llc_storef(float* p, float v) {
  __hip_atomic_store(p, v, __ATOMIC_RELAXED, SCOPE);
}
// vectorized LLC loads via explicit sc0|sc1 (float4 asm OUTPUTS ok; no asm stores)
__device__ __forceinline__ float4 llc_ld4(const float* p) {
  float4 r;
  asm volatile("global_load_dwordx4 %0, %1, off sc0 sc1\n\ts_waitcnt vmcnt(0)"
               : "=&v"(r) : "v"(p) : "memory");
  return r;
}
__device__ __forceinline__ void llc_ld4x4(const float* p0, const float* p1,
                                          const float* p2, const float* p3,
                                          float4& a, float4& b, float4& c, float4& d) {
  asm volatile(
      "global_load_dwordx4 %0, %4, off sc0 sc1\n\t"
      "global_load_dwordx4 %1, %5, off sc0 sc1\n\t"
      "global_load_dwordx4 %2, %6, off sc0 sc1\n\t"
      "global_load_dwordx4 %3, %7, off sc0 sc1\n\t"
      "s_waitcnt vmcnt(0)"
      : "=&v"(a), "=&v"(b), "=&v"(c), "=&v"(d)
      : "v"(p0), "v"(p1), "v"(p2), "v"(p3) : "memory");
}

// 16-block group barrier: relaxed LLC flags; vmcnt(0) drained before flag store
__device__ __forceinline__ void group_barrier16(unsigned* flags_g, int j, unsigned tgt) {
  asm volatile("s_waitcnt vmcnt(0)" ::: "memory");
  __syncthreads();
  if (threadIdx.x == 0)
    __hip_atomic_store(&flags_g[j * 32], tgt, __ATOMIC_RELAXED, SCOPE);
  if (threadIdx.x < 16) {
    long spins = 0;
    while (__hip_atomic_load(&flags_g[threadIdx.x * 32], __ATOMIC_RELAXED, SCOPE) < tgt) {
      __builtin_amdgcn_s_sleep(1);
      if (++spins > 50000000L) __builtin_trap();   // residency/deadlock tripwire
    }
  }
  __syncthreads();
  asm volatile("" ::: "memory");
}

#define DOT4(acc, w4, x4) \
  acc = fmaf((w4).x, (x4).x, fmaf((w4).y, (x4).y, fmaf((w4).z, (x4).z, fmaf((w4).w, (x4).w, (acc)))))

__global__ void __launch_bounds__(NTHR, 2)
decoder_main(const float* __restrict__ emb, const float* __restrict__ dec0,
             const float* __restrict__ h0,  const float* __restrict__ c0,
             const float* __restrict__ ctxg,const float* __restrict__ Wi,
             const float* __restrict__ bi,  const float* __restrict__ Wh,
             const float* __restrict__ bh,  const float* __restrict__ Wo,
             const float* __restrict__ bo,  const float* __restrict__ Wain,
             const float* __restrict__ bain,const float* __restrict__ Wactx,
             const float* __restrict__ bactx,const float* __restrict__ Vv,
             float* __restrict__ out, unsigned* __restrict__ flags,
             float* __restrict__ wsd)
{
  extern __shared__ float sm[];
  float* ctx    = sm + OFF_CTX;
  float* scr    = sm + OFF_SCR;
  float* x_s    = sm + OFF_SCR;     // alias (phase A tail)
  float* inp_s  = sm + OFF_INP;
  float* s_s    = sm + OFF_SS;
  float* e_s    = sm + OFF_ES;
  float* mask_s = sm + OFF_MK;
  float* V_s    = sm + OFF_VS;
  float* gsum   = sm + OFF_GS;
  float* stats_s= sm + OFF_ST;
  float* bain_s = sm + OFF_BA;
  float* htl_s  = sm + OFF_HTL;
  float* bo_s   = sm + OFF_BO;
  float* hid_s  = sm + OFF_HID;

  const int tid = threadIdx.x, bid = blockIdx.x;
  const int gq = bid >> 4, j = bid & 15;     // 32 groups x 16 blocks
  const int bbj = j >> 3, ck = j & 7;        // 2 batches x 8 l-slices
  const int b_ctx = gq * 2 + bbj;
  const int l0 = ck * 64;

  // role indices (256 threads)
  const int team = tid >> 2, seg4 = tid & 3;       // gates: 4 thr/row, 64 rows
  const int gteam = team >> 4, hloc = team & 15;
  const int r_abs = gteam * 256 + j * 16 + hloc;   // gate row (g, h=j*16+hloc)
  const int hq = tid & 63, lg = tid >> 6;          // scores/PV: lane=h-quad, 4 waves

  unsigned* flags_g = flags + gq * (16 * 32);
  float* wsg = wsd + (size_t)gq * GQ_STRIDE;

  // L2-streamed weight row pointers (XCD j-locality keeps them L2-hot)
  const float* wiRow = Wi + (size_t)r_abs * En;
  const float* whRow = Wh + (size_t)r_abs * Hn;
  const float* waRow = Wain + (size_t)tid * Hn + j * 16;
  const float* woRow = Wo + (size_t)tid * (2 * Hn);   // full Wo: 1 thread/row
  const float bias_g = bi[r_abs] + bh[r_abs];

  // cell state: tid<32 owns (bb=tid>>4, h=j*16+(tid&15))
  float cst = 0.0f;
  if (tid < 32) cst = c0[(size_t)(gq * 2 + (tid >> 4)) * Hn + j * 16 + (tid & 15)];

  if (tid < 64) mask_s[tid] = 1.0f;
  V_s[tid] = Vv[tid];
  bain_s[tid] = bain[tid];
  bo_s[tid] = bo[tid];

  // ---- one-time ctx_proj slice into LDS (batch b_ctx, l in [l0,l0+64)) ----
  {
    const int gc = tid & 31, lgi = tid >> 5;
    float acc[8][8];
    #pragma unroll
    for (int a2 = 0; a2 < 8; ++a2)
      #pragma unroll
      for (int b2 = 0; b2 < 8; ++b2) acc[a2][b2] = 0.0f;
    float* stg_c = scr;          // [4][64]
    float* stg_w = scr + 256;    // [4][256]
    for (int kc = 0; kc < 64; ++kc) {
      __syncthreads();
      {
        const int k = tid >> 6, l = tid & 63;
        stg_c[k * 64 + l] = ctxg[((size_t)(b_ctx * Ln + l0 + l)) * Hn + kc * 4 + k];
      }
      #pragma unroll
      for (int it = 0; it < 4; ++it) {
        const int i = tid + it * 256;
        const int k = i >> 8, gg = i & 255;
        stg_w[k * 256 + gg] = Wactx[(size_t)gg * Hn + kc * 4 + k];
      }
      __syncthreads();
      #pragma unroll
      for (int kk = 0; kk < 4; ++kk) {
        float cl[8], wgt[8];
        #pragma unroll
        for (int jj = 0; jj < 8; ++jj) cl[jj] = stg_c[kk * 64 + lgi * 8 + jj];
        #pragma unroll
        for (int jj = 0; jj < 8; ++jj) wgt[jj] = stg_w[kk * 256 + gc * 8 + jj];
        #pragma unroll
        for (int li = 0; li < 8; ++li)
          #pragma unroll
          for (int gi = 0; gi < 8; ++gi)
            acc[li][gi] = fmaf(cl[li], wgt[gi], acc[li][gi]);
      }
    }
    __syncthreads();
    #pragma unroll
    for (int li = 0; li < 8; ++li)
      #pragma unroll
      for (int gi = 0; gi < 8; ++gi)
        ctx[(lgi * 8 + li) * CTX_LD + gc * 8 + gi] = acc[li][gi] + bactx[gc * 8 + gi];
  }
  __syncthreads();

  unsigned tgt = 1;

  for (int t = 0; t <= Tn; ++t) {
    // ===== Phase A: deferred outputs of step t-1, then gates/cell of step t =====
    int wq0 = 0, wq1 = 0;
    if (t > 0) {
      const int php = (t & 1) ^ 1;     // parity h_t was published at (A_{t-1})
      float4 asum = make_float4(0, 0, 0, 0);
      if (tid < 128) {                 // att partials: (bb, h-quad), 8 ck each
        const int bbx = tid >> 6, q = tid & 63;
        const float* ab = wsg + GQ_ATT + bbx * 2048 + q * 4;
        float4 a0, a1, a2, a3, b0, b1, b2, b3;
        llc_ld4x4(ab, ab + 256, ab + 512, ab + 768, a0, a1, a2, a3);
        llc_ld4x4(ab + 1024, ab + 1280, ab + 1536, ab + 1792, b0, b1, b2, b3);
        asum.x = ((a0.x + a1.x) + (a2.x + a3.x)) + ((b0.x + b1.x) + (b2.x + b3.x));
        asum.y = ((a0.y + a1.y) + (a2.y + a3.y)) + ((b0.y + b1.y) + (b2.y + b3.y));
        asum.z = ((a0.z + a1.z) + (a2.z + a3.z)) + ((b0.z + b1.z) + (b2.z + b3.z));
        asum.w = ((a0.w + a1.w) + (a2.w + a3.w)) + ((b0.w + b1.w) + (b2.w + b3.w));
      } else {                         // h_t (both batches) -> u tail; stats
        const int tid2 = tid - 128;
        const int bbx = tid2 >> 6, h4 = tid2 & 63;
        const float4 hv = llc_ld4(wsg + GQ_HT + php * 512 + bbx * 256 + h4 * 4);
        *(float4*)&scr[bbx * UPAD + 256 + h4 * 4] = hv;
        if (tid2 < 16) {
          const float4 st = llc_ld4(wsg + GQ_STATS + tid2 * 4);
          *(float4*)&stats_s[tid2 * 4] = st;
        }
      }
      __syncthreads();
      // merge stats (redundant on all threads)
      float Sb[2]; int wq[2];
      #pragma unroll
      for (int bb = 0; bb < 2; ++bb) {
        float Ssum = 0.0f;
        #pragma unroll
        for (int c2 = 0; c2 < 8; ++c2) Ssum += stats_s[(bb * 8 + c2) * 4];
        Sb[bb] = Ssum;
        float bv = stats_s[(bb * 8 + 0) * 4 + 1];
        int bI = (int)stats_s[(bb * 8 + 0) * 4 + 2];
        #pragma unroll
        for (int c2 = 1; c2 < 8; ++c2) {
          const float v2 = stats_s[(bb * 8 + c2) * 4 + 1];
          const int i2 = (int)stats_s[(bb * 8 + c2) * 4 + 2];
          if (v2 > bv || (v2 == bv && i2 < bI)) { bv = v2; bI = i2; }
        }
        wq[bb] = bI;
      }
      wq0 = wq[0]; wq1 = wq[1];
      const float Sown = (bbj == 0) ? Sb[0] : Sb[1];
      const int wown = (bbj == 0) ? wq[0] : wq[1];
      // alphas + pointer of step t-1 (e_s persists from B_{t-1})
      if (tid < 16) {
        const float4 e4 = *(const float4*)&e_s[tid * 4];
        *(float4*)&out[(size_t)b_ctx * Ln * Ln + (size_t)(t - 1) * Ln + l0 + tid * 4] =
            make_float4(e4.x / Sown, e4.y / Sown, e4.z / Sown, e4.w / Sown);
      }
      if (tid == 0) {
        if (wown >= l0 && wown < l0 + 64) mask_s[wown - l0] = 0.0f;
        if (ck == 0) out[PTR_OFF + (size_t)b_ctx * Ln + (t - 1)] = (float)wown;
      }
      // u head (att/S)
      if (tid < 128) {
        const int bbx = tid >> 6, q = tid & 63;
        const float Sx = (bbx == 0) ? Sb[0] : Sb[1];
        *(float4*)&scr[bbx * UPAD + q * 4] =
            make_float4(asum.x / Sx, asum.y / Sx, asum.z / Sx, asum.w / Sx);
      }
      __syncthreads();
      // full-Wo hidden for BOTH batches (1 thread/row; u broadcast from LDS)
      {
        float acc0 = 0.0f, acc1 = 0.0f;
        #pragma unroll 8
        for (int k = 0; k < 128; ++k) {
          const float4 w4 = *(const float4*)&woRow[k * 4];
          const float4 xa = *(const float4*)&scr[k * 4];
          const float4 xb = *(const float4*)&scr[UPAD + k * 4];
          DOT4(acc0, w4, xa);
          DOT4(acc1, w4, xb);
        }
        const float h0v = tanhf(acc0 + bo_s[tid]);
        const float h1v = tanhf(acc1 + bo_s[tid]);
        hid_s[tid] = h0v;
        hid_s[256 + tid] = h1v;
        if (t == Tn) {
          out[HF_OFF + (size_t)(gq * 2 + 0) * Hn + tid] = h0v;
          out[HF_OFF + (size_t)(gq * 2 + 1) * Hn + tid] = h1v;
        }
      }
    }

    if (t < Tn) {
      __syncthreads();   // hid_s ready; scr reusable for x
      // x build
      if (tid < 64) {
        const int bbx = tid >> 5, k4 = tid & 31;
        const int gb = gq * 2 + bbx;
        float4 v;
        if (t == 0) v = *(const float4*)&dec0[(size_t)gb * En + k4 * 4];
        else {
          const int wsel = (bbx == 0) ? wq0 : wq1;
          v = *(const float4*)&emb[((size_t)gb * Ln + wsel) * En + k4 * 4];
        }
        *(float4*)&x_s[bbx * XPAD + k4 * 4] = v;
      } else if (tid < 192) {
        const int tid2 = tid - 64, bbx = tid2 >> 6, h4 = tid2 & 63;
        float4 v;
        if (t == 0) v = *(const float4*)&h0[(size_t)(gq * 2 + bbx) * Hn + h4 * 4];
        else        v = *(const float4*)&hid_s[bbx * 256 + h4 * 4];
        *(float4*)&x_s[bbx * XPAD + 128 + h4 * 4] = v;
      }
      __syncthreads();
      // gates GEMV (L2-streamed, load-once-use-twice)
      {
        float acc0 = 0.0f, acc1 = 0.0f;
        #pragma unroll
        for (int k = 0; k < 8; ++k) {
          const float4 w4 = *(const float4*)&wiRow[k * 16 + seg4 * 4];
          const float4 xa = *(const float4*)&x_s[k * 16 + seg4 * 4];
          const float4 xb = *(const float4*)&x_s[XPAD + k * 16 + seg4 * 4];
          DOT4(acc0, w4, xa);
          DOT4(acc1, w4, xb);
        }
        #pragma unroll
        for (int k = 0; k < 16; ++k) {
          const float4 w4 = *(const float4*)&whRow[k * 16 + seg4 * 4];
          const float4 xa = *(const float4*)&x_s[128 + k * 16 + seg4 * 4];
          const float4 xb = *(const float4*)&x_s[XPAD + 128 + k * 16 + seg4 * 4];
          DOT4(acc0, w4, xa);
          DOT4(acc1, w4, xb);
        }
        acc0 += __shfl_xor(acc0, 1, 64);
        acc0 += __shfl_xor(acc0, 2, 64);
        acc1 += __shfl_xor(acc1, 1, 64);
        acc1 += __shfl_xor(acc1, 2, 64);
        if (seg4 == 0) {
          gsum[team] = acc0 + bias_g;
          gsum[64 + team] = acc1 + bias_g;
        }
      }
      __syncthreads();
      if (tid < 32) {
        const int bbx = tid >> 4, hx = tid & 15;
        const float iv = gsum[bbx * 64 + hx];
        const float fv = gsum[bbx * 64 + 16 + hx];
        const float gv = gsum[bbx * 64 + 32 + hx];
        const float ov = gsum[bbx * 64 + 48 + hx];
        const float cn = sigmoidf_(fv) * cst + sigmoidf_(iv) * tanhf(gv);
        const float htv = sigmoidf_(ov) * tanhf(cn);
        cst = cn;
        htl_s[bbx * 16 + hx] = htv;
        llc_storef(wsg + GQ_HT + (t & 1) * 512 + bbx * 256 + j * 16 + hx, htv);
        if (t == Tn - 1) out[CF_OFF + (size_t)(gq * 2 + bbx) * Hn + j * 16 + hx] = cn;
      }
      __syncthreads();
      // inp partials over own h-slice
      {
        float a0 = 0.0f, a1 = 0.0f;
        #pragma unroll
        for (int k = 0; k < 4; ++k) {
          const float4 w4 = *(const float4*)&waRow[k * 4];
          const float4 xa = *(const float4*)&htl_s[k * 4];
          const float4 xb = *(const float4*)&htl_s[16 + k * 4];
          DOT4(a0, w4, xa);
          DOT4(a1, w4, xb);
        }
        llc_storef(wsg + GQ_INPP + tid * 16 + j, a0);
        llc_storef(wsg + GQ_INPP + 4096 + tid * 16 + j, a1);
      }
      group_barrier16(flags_g, j, tgt++);

      // ===== Phase B: inp gather, scores, softmax stats, PV =====
      {
        const float* ib = wsg + GQ_INPP + bbj * 4096 + tid * 16;
        float4 a0, a1, a2, a3;
        llc_ld4x4(ib, ib + 4, ib + 8, ib + 12, a0, a1, a2, a3);
        const float s01 = ((a0.x + a0.y) + (a0.z + a0.w)) + ((a1.x + a1.y) + (a1.z + a1.w));
        const float s23 = ((a2.x + a2.y) + (a2.z + a2.w)) + ((a3.x + a3.y) + (a3.z + a3.w));
        inp_s[tid] = s01 + s23 + bain_s[tid];
      }
      __syncthreads();
      {
        const float4 in4 = *(const float4*)&inp_s[hq * 4];
        const float4 v4  = *(const float4*)&V_s[hq * 4];
        #pragma unroll
        for (int pass = 0; pass < 2; ++pass) {
          const int lb = pass * 32 + lg * 8;
          float p0, p1, p2, p3, p4, p5, p6, p7;
          #define SCORE_P(dst, li)                                           \
            {                                                                \
              const float4 c4 = *(const float4*)&ctx[(lb + (li)) * CTX_LD + hq * 4]; \
              float p;                                                       \
              p = v4.x * fast_tanh(in4.x + c4.x);                            \
              p = fmaf(v4.y, fast_tanh(in4.y + c4.y), p);                    \
              p = fmaf(v4.z, fast_tanh(in4.z + c4.z), p);                    \
              p = fmaf(v4.w, fast_tanh(in4.w + c4.w), p);                    \
              dst = p;                                                       \
            }
          SCORE_P(p0, 0) SCORE_P(p1, 1) SCORE_P(p2, 2) SCORE_P(p3, 3)
          SCORE_P(p4, 4) SCORE_P(p5, 5) SCORE_P(p6, 6) SCORE_P(p7, 7)
          #undef SCORE_P
          const bool hi32 = (hq & 32) != 0;
          float s, q0, q1, q2, q3, r0, r1, t0;
          s = hi32 ? p0 : p4; s = __shfl_xor(s, 32, 64); q0 = (hi32 ? p4 : p0) + s;
          s = hi32 ? p1 : p5; s = __shfl_xor(s, 32, 64); q1 = (hi32 ? p5 : p1) + s;
          s = hi32 ? p2 : p6; s = __shfl_xor(s, 32, 64); q2 = (hi32 ? p6 : p2) + s;
          s = hi32 ? p3 : p7; s = __shfl_xor(s, 32, 64); q3 = (hi32 ? p7 : p3) + s;
          const bool hi16 = (hq & 16) != 0;
          s = hi16 ? q0 : q2; s = __shfl_xor(s, 16, 64); r0 = (hi16 ? q2 : q0) + s;
          s = hi16 ? q1 : q3; s = __shfl_xor(s, 16, 64); r1 = (hi16 ? q3 : q1) + s;
          const bool hi8 = (hq & 8) != 0;
          s = hi8 ? r0 : r1; s = __shfl_xor(s, 8, 64); t0 = (hi8 ? r1 : r0) + s;
          t0 += __shfl_xor(t0, 4, 64);
          t0 += __shfl_xor(t0, 2, 64);
          t0 += __shfl_xor(t0, 1, 64);
          if ((hq & 7) == 0) {
            const int l = lb + ((hq >> 3) & 7);
            s_s[l] = (mask_s[l] == 0.0f) ? -INFINITY : t0;
          }
        }
      }
      __syncthreads();
      if (tid < 64) {
        const float sv = s_s[tid];
        const float e = expf(sv);          // masked -> exp(-inf)=0; |s|<=~10 safe
        e_s[tid] = e;
        float ssum = e;
        #pragma unroll
        for (int m = 1; m < 64; m <<= 1) ssum += __shfl_xor(ssum, m, 64);
        float cv = sv; int ci = tid;
        #pragma unroll
        for (int m = 1; m < 64; m <<= 1) {
          const float ov = __shfl_xor(cv, m, 64);
          const int   oi = __shfl_xor(ci, m, 64);
          if (ov > cv || (ov == cv && oi < ci)) { cv = ov; ci = oi; }
        }
        if (tid == 0) {
          float* stb = wsg + GQ_STATS + (bbj * 8 + ck) * 4;
          llc_storef(stb + 0, ssum);
          llc_storef(stb + 1, cv);
          llc_storef(stb + 2, (float)(l0 + ci));
        }
      }
      __syncthreads();
      // PV: 16 l's per thread, partials scr[4][256]
      {
        float p0 = 0, p1 = 0, p2 = 0, p3 = 0;
        #pragma unroll
        for (int pass = 0; pass < 2; ++pass) {
          #pragma unroll
          for (int li = 0; li < 8; ++li) {
            const int l = pass * 32 + lg * 8 + li;
            const float ev = e_s[l];
            const float4 c4 = *(const float4*)&ctx[l * CTX_LD + hq * 4];
            p0 = fmaf(ev, c4.x, p0);
            p1 = fmaf(ev, c4.y, p1);
            p2 = fmaf(ev, c4.z, p2);
            p3 = fmaf(ev, c4.w, p3);
          }
        }
        __syncthreads();   // scr free (x staging consumed)
        *(float4*)&scr[lg * 256 + hq * 4] = make_float4(p0, p1, p2, p3);
      }
      __syncthreads();
      {
        float a = 0.0f;
        #pragma unroll
        for (int r2 = 0; r2 < 4; ++r2) a += scr[r2 * 256 + tid];
        llc_storef(wsg + GQ_ATT + (bbj * 8 + ck) * 256 + tid, a);
      }
      group_barrier16(flags_g, j, tgt++);
    }
  }
}

extern "C" void kernel_launch(void* const* d_in, const int* in_sizes, int n_in,
                              void* d_out, int out_size, void* d_ws, size_t ws_size,
                              hipStream_t stream) {
  (void)in_sizes; (void)n_in; (void)out_size; (void)ws_size;
  (void)hipFuncSetAttribute(reinterpret_cast<const void*>(decoder_main),
                            hipFuncAttributeMaxDynamicSharedMemorySize, SMEM_FL * 4);
  (void)hipMemsetAsync(d_ws, 0, 65536, stream);   // zero barrier flags each launch/replay

  const float* emb   = (const float*)d_in[0];
  const float* dec0  = (const float*)d_in[1];
  const float* h0    = (const float*)d_in[2];
  const float* c0    = (const float*)d_in[3];
  const float* ctxg  = (const float*)d_in[4];
  const float* Wi    = (const float*)d_in[5];
  const float* bi    = (const float*)d_in[6];
  const float* Wh    = (const float*)d_in[7];
  const float* bh    = (const float*)d_in[8];
  const float* Wo    = (const float*)d_in[9];
  const float* bo    = (const float*)d_in[10];
  const float* Wain  = (const float*)d_in[11];
  const float* bain  = (const float*)d_in[12];
  const float* Wactx = (const float*)d_in[13];
  const float* bactx = (const float*)d_in[14];
  const float* V     = (const float*)d_in[15];

  unsigned* flags = (unsigned*)d_ws;
  float* wsd = (float*)((char*)d_ws + 65536);

  decoder_main<<<NBLK, NTHR, SMEM_FL * 4, stream>>>(
      emb, dec0, h0, c0, ctxg, Wi, bi, Wh, bh, Wo, bo, Wain, bain, Wactx, bactx, V,
      (float*)d_out, flags, wsd);
}

// Round 14
// 11441.797 us; speedup vs baseline: 1.9343x; 1.9343x over previous
//
#include <hip/hip_runtime.h>
#include <math.h>

#define SCOPE __HIP_MEMORY_SCOPE_AGENT

constexpr int Bn = 64, Ln = 512, En = 128, Hn = 256, Tn = 512;
constexpr int NBLK = 512, NTHR = 256;     // 2 blocks/CU; co-resident = group-mates (j, j+8)
constexpr int CTX_LD = 256, XPAD = 384, UPAD = 520;

// ---- LDS layout (floats) ----
constexpr int OFF_CTX = 0;                  // [64][256] ctx slice
constexpr int OFF_SCR = 64 * CTX_LD;        // 2048: init stage / x / PV partials / u
constexpr int OFF_INP = OFF_SCR + 2048;     // inp (own batch) [256]
constexpr int OFF_SS  = OFF_INP + 256;      // scores [64]
constexpr int OFF_ES  = OFF_SS + 64;        // e [64]
constexpr int OFF_MK  = OFF_ES + 64;        // mask [64]
constexpr int OFF_VS  = OFF_MK + 64;        // V [256]
constexpr int OFF_GS  = OFF_VS + 256;       // gate pre-activations [2bb][64]
constexpr int OFF_ST  = OFF_GS + 128;       // stats [16][4]
constexpr int OFF_BA  = OFF_ST + 64;        // bain [256]
constexpr int OFF_HTL = OFF_BA + 256;       // own-slice h_t [2][16]
constexpr int SMEM_FL = OFF_HTL + 32;       // 19680 floats = 78720 B -> 2 blocks/CU

// ---- output layout ----
constexpr size_t PTR_OFF = (size_t)Bn * Ln * Ln;
constexpr size_t HF_OFF  = PTR_OFF + (size_t)Bn * Ln;
constexpr size_t CF_OFF  = HF_OFF + (size_t)Bn * Hn;

// ---- ws: [0,64KB) flags (32 groups x 16 x 32 uints); then per-group floats ----
constexpr int GQ_HT    = 0;      // h_t [2][256]
constexpr int GQ_HID   = 512;    // hidden [2][256]
constexpr int GQ_ATT   = 1024;   // att partials [2bb*8ck][256]
constexpr int GQ_STATS = 5120;   // [16][4] {S, candv, candi, pad}
constexpr int GQ_INPP  = 5184;   // inp partials [2bb][256g][16j]
constexpr int GQ_STRIDE = 5184 + 8192;   // 13376 floats/group

__device__ __forceinline__ float fast_tanh(float x) {
  const float e = __expf(2.0f * x);
  return 1.0f - __fdividef(2.0f, 1.0f + e);
}
__device__ __forceinline__ float sigmoidf_(float x) {
  return 1.0f / (1.0f + expf(-x));
}
__device__ __forceinline__ void llc_storef(float* p, float v) {
  __hip_atomic_store(p, v, __ATOMIC_RELAXED, SCOPE);
}
// vectorized LLC loads via explicit sc0|sc1 (float4 asm OUTPUTS ok; no asm stores)
__device__ __forceinline__ float4 llc_ld4(const float* p) {
  float4 r;
  asm volatile("global_load_dwordx4 %0, %1, off sc0 sc1\n\ts_waitcnt vmcnt(0)"
               : "=&v"(r) : "v"(p) : "memory");
  return r;
}
__device__ __forceinline__ void llc_ld4x4(const float* p0, const float* p1,
                                          const float* p2, const float* p3,
                                          float4& a, float4& b, float4& c, float4& d) {
  asm volatile(
      "global_load_dwordx4 %0, %4, off sc0 sc1\n\t"
      "global_load_dwordx4 %1, %5, off sc0 sc1\n\t"
      "global_load_dwordx4 %2, %6, off sc0 sc1\n\t"
      "global_load_dwordx4 %3, %7, off sc0 sc1\n\t"
      "s_waitcnt vmcnt(0)"
      : "=&v"(a), "=&v"(b), "=&v"(c), "=&v"(d)
      : "v"(p0), "v"(p1), "v"(p2), "v"(p3) : "memory");
}
// 9 loads, ONE drain (P3 gather: 8 att partial chunks + h_t) — single serial trip
__device__ __forceinline__ void llc_ld9(const float* p0, const float* p1,
                                        const float* p2, const float* p3,
                                        const float* p4, const float* p5,
                                        const float* p6, const float* p7,
                                        const float* p8,
                                        float4& a, float4& b, float4& c, float4& d,
                                        float4& e, float4& f, float4& g, float4& h,
                                        float4& i) {
  asm volatile(
      "global_load_dwordx4 %0, %9, off sc0 sc1\n\t"
      "global_load_dwordx4 %1, %10, off sc0 sc1\n\t"
      "global_load_dwordx4 %2, %11, off sc0 sc1\n\t"
      "global_load_dwordx4 %3, %12, off sc0 sc1\n\t"
      "global_load_dwordx4 %4, %13, off sc0 sc1\n\t"
      "global_load_dwordx4 %5, %14, off sc0 sc1\n\t"
      "global_load_dwordx4 %6, %15, off sc0 sc1\n\t"
      "global_load_dwordx4 %7, %16, off sc0 sc1\n\t"
      "global_load_dwordx4 %8, %17, off sc0 sc1\n\t"
      "s_waitcnt vmcnt(0)"
      : "=&v"(a), "=&v"(b), "=&v"(c), "=&v"(d), "=&v"(e), "=&v"(f), "=&v"(g),
        "=&v"(h), "=&v"(i)
      : "v"(p0), "v"(p1), "v"(p2), "v"(p3), "v"(p4), "v"(p5), "v"(p6), "v"(p7),
        "v"(p8) : "memory");
}

// 16-block group barrier: relaxed LLC flags; vmcnt(0) drained before flag store
__device__ __forceinline__ void group_barrier16(unsigned* flags_g, int j, unsigned tgt) {
  asm volatile("s_waitcnt vmcnt(0)" ::: "memory");
  __syncthreads();
  if (threadIdx.x == 0)
    __hip_atomic_store(&flags_g[j * 32], tgt, __ATOMIC_RELAXED, SCOPE);
  if (threadIdx.x < 16) {
    long spins = 0;
    while (__hip_atomic_load(&flags_g[threadIdx.x * 32], __ATOMIC_RELAXED, SCOPE) < tgt) {
      __builtin_amdgcn_s_sleep(1);
      if (++spins > 50000000L) __builtin_trap();   // residency/deadlock tripwire
    }
  }
  __syncthreads();
  asm volatile("" ::: "memory");
}

#define DOT4(acc, w4, x4) \
  acc = fmaf((w4).x, (x4).x, fmaf((w4).y, (x4).y, fmaf((w4).z, (x4).z, fmaf((w4).w, (x4).w, (acc)))))

__global__ void __launch_bounds__(NTHR, 2)
decoder_main(const float* __restrict__ emb, const float* __restrict__ dec0,
             const float* __restrict__ h0,  const float* __restrict__ c0,
             const float* __restrict__ ctxg,const float* __restrict__ Wi,
             const float* __restrict__ bi,  const float* __restrict__ Wh,
             const float* __restrict__ bh,  const float* __restrict__ Wo,
             const float* __restrict__ bo,  const float* __restrict__ Wain,
             const float* __restrict__ bain,const float* __restrict__ Wactx,
             const float* __restrict__ bactx,const float* __restrict__ Vv,
             float* __restrict__ out, unsigned* __restrict__ flags,
             float* __restrict__ wsd)
{
  extern __shared__ float sm[];
  float* ctx    = sm + OFF_CTX;
  float* scr    = sm + OFF_SCR;
  float* x_s    = sm + OFF_SCR;     // alias (P1)
  float* inp_s  = sm + OFF_INP;
  float* s_s    = sm + OFF_SS;
  float* e_s    = sm + OFF_ES;
  float* mask_s = sm + OFF_MK;
  float* V_s    = sm + OFF_VS;
  float* gsum   = sm + OFF_GS;
  float* stats_s= sm + OFF_ST;
  float* bain_s = sm + OFF_BA;
  float* htl_s  = sm + OFF_HTL;

  const int tid = threadIdx.x, bid = blockIdx.x;
  // co-residency-aligned mapping: co-resident blocks (bid, bid+256) share gq
  // (j and j+8) -> group-mates sync together, symmetric contention, low skew.
  const int gq = bid & 31, j = bid >> 5;     // 32 groups x 16 blocks
  const int bbj = j >> 3, ck = j & 7;        // 2 batches x 8 l-slices
  const int b_ctx = gq * 2 + bbj;
  const int l0 = ck * 64;

  // role indices (256 threads)
  const int team = tid >> 2, seg4 = tid & 3;       // gates: 4 thr/row, 64 rows
  const int gteam = team >> 4, hloc = team & 15;
  const int r_abs = gteam * 256 + j * 16 + hloc;   // gate row (g, h=j*16+hloc)
  const int r16loc = tid >> 4, seg16 = tid & 15;   // Wo: 16 thr/row, 16 rows
  const int r16 = j * 16 + r16loc;
  const int hq = tid & 63, lg = tid >> 6;          // scores/PV: lane=h-quad, 4 waves

  unsigned* flags_g = flags + gq * (16 * 32);
  float* wsg = wsd + (size_t)gq * GQ_STRIDE;

  // L2-streamed weight row pointers (L2-hot; all j's per XCD now, 2.3MB < 4MB)
  const float* wiRow = Wi + (size_t)r_abs * En;
  const float* whRow = Wh + (size_t)r_abs * Hn;
  const float* waRow = Wain + (size_t)tid * Hn + j * 16;
  const float* woRow = Wo + (size_t)r16 * (2 * Hn);
  const float bias_g = bi[r_abs] + bh[r_abs];
  const float bo_r = bo[r16];

  // cell state: tid<32 owns (bb=tid>>4, h=j*16+(tid&15))
  float cst = 0.0f;
  if (tid < 32) cst = c0[(size_t)(gq * 2 + (tid >> 4)) * Hn + j * 16 + (tid & 15)];

  if (tid < 64) mask_s[tid] = 1.0f;
  V_s[tid] = Vv[tid];
  bain_s[tid] = bain[tid];

  // ---- one-time ctx_proj slice into LDS (batch b_ctx, l in [l0,l0+64)) ----
  {
    const int gc = tid & 31, lgi = tid >> 5;
    float acc[8][8];
    #pragma unroll
    for (int a2 = 0; a2 < 8; ++a2)
      #pragma unroll
      for (int b2 = 0; b2 < 8; ++b2) acc[a2][b2] = 0.0f;
    float* stg_c = scr;          // [4][64]
    float* stg_w = scr + 256;    // [4][256]
    for (int kc = 0; kc < 64; ++kc) {
      __syncthreads();
      {
        const int k = tid >> 6, l = tid & 63;
        stg_c[k * 64 + l] = ctxg[((size_t)(b_ctx * Ln + l0 + l)) * Hn + kc * 4 + k];
      }
      #pragma unroll
      for (int it = 0; it < 4; ++it) {
        const int i = tid + it * 256;
        const int k = i >> 8, gg = i & 255;
        stg_w[k * 256 + gg] = Wactx[(size_t)gg * Hn + kc * 4 + k];
      }
      __syncthreads();
      #pragma unroll
      for (int kk = 0; kk < 4; ++kk) {
        float cl[8], wgt[8];
        #pragma unroll
        for (int jj = 0; jj < 8; ++jj) cl[jj] = stg_c[kk * 64 + lgi * 8 + jj];
        #pragma unroll
        for (int jj = 0; jj < 8; ++jj) wgt[jj] = stg_w[kk * 256 + gc * 8 + jj];
        #pragma unroll
        for (int li = 0; li < 8; ++li)
          #pragma unroll
          for (int gi = 0; gi < 8; ++gi)
            acc[li][gi] = fmaf(cl[li], wgt[gi], acc[li][gi]);
      }
    }
    __syncthreads();
    #pragma unroll
    for (int li = 0; li < 8; ++li)
      #pragma unroll
      for (int gi = 0; gi < 8; ++gi)
        ctx[(lgi * 8 + li) * CTX_LD + gc * 8 + gi] = acc[li][gi] + bactx[gc * 8 + gi];
  }
  __syncthreads();

  unsigned tgt = 1;
  int w0 = 0, w1 = 0;

  for (int t = 0; t < Tn; ++t) {
    // ========== P1: x stage, gates GEMV (L2-streamed, load-once-use-twice) ==========
    {
      if (tid < 128) {           // hidden/h0 -> x[bb][128..384]
        const int bbx = tid >> 6, h4 = tid & 63;
        float4 v;
        if (t == 0) v = *(const float4*)&h0[(size_t)(gq * 2 + bbx) * Hn + h4 * 4];
        else        v = llc_ld4(wsg + GQ_HID + bbx * 256 + h4 * 4);
        *(float4*)&x_s[bbx * XPAD + 128 + h4 * 4] = v;
      } else if (tid < 192) {    // emb/dec0 -> x[bb][0..128]
        const int i2 = tid - 128, bbx = i2 >> 5, k4 = i2 & 31;
        const int gb = gq * 2 + bbx;
        float4 v;
        if (t == 0) v = *(const float4*)&dec0[(size_t)gb * En + k4 * 4];
        else {
          const int wsel = (bbx == 0) ? w0 : w1;
          v = *(const float4*)&emb[((size_t)gb * Ln + wsel) * En + k4 * 4];
        }
        *(float4*)&x_s[bbx * XPAD + k4 * 4] = v;
      }
      __syncthreads();
      {
        float acc0 = 0.0f, acc1 = 0.0f;
        #pragma unroll
        for (int k = 0; k < 8; ++k) {
          const float4 w4 = *(const float4*)&wiRow[k * 16 + seg4 * 4];
          const float4 xa = *(const float4*)&x_s[k * 16 + seg4 * 4];
          const float4 xb = *(const float4*)&x_s[XPAD + k * 16 + seg4 * 4];
          DOT4(acc0, w4, xa);
          DOT4(acc1, w4, xb);
        }
        #pragma unroll
        for (int k = 0; k < 16; ++k) {
          const float4 w4 = *(const float4*)&whRow[k * 16 + seg4 * 4];
          const float4 xa = *(const float4*)&x_s[128 + k * 16 + seg4 * 4];
          const float4 xb = *(const float4*)&x_s[XPAD + 128 + k * 16 + seg4 * 4];
          DOT4(acc0, w4, xa);
          DOT4(acc1, w4, xb);
        }
        acc0 += __shfl_xor(acc0, 1, 64);
        acc0 += __shfl_xor(acc0, 2, 64);
        acc1 += __shfl_xor(acc1, 1, 64);
        acc1 += __shfl_xor(acc1, 2, 64);
        if (seg4 == 0) {
          gsum[team] = acc0 + bias_g;         // [bb=0][g*16+h]
          gsum[64 + team] = acc1 + bias_g;    // [bb=1]
        }
      }
      __syncthreads();
      if (tid < 32) {
        const int bbx = tid >> 4, hx = tid & 15;
        const float iv = gsum[bbx * 64 + hx];
        const float fv = gsum[bbx * 64 + 16 + hx];
        const float gv = gsum[bbx * 64 + 32 + hx];
        const float ov = gsum[bbx * 64 + 48 + hx];
        const float cn = sigmoidf_(fv) * cst + sigmoidf_(iv) * tanhf(gv);
        const float htv = sigmoidf_(ov) * tanhf(cn);
        cst = cn;
        htl_s[bbx * 16 + hx] = htv;
        llc_storef(wsg + GQ_HT + bbx * 256 + j * 16 + hx, htv);
        if (t == Tn - 1) out[CF_OFF + (size_t)(gq * 2 + bbx) * Hn + j * 16 + hx] = cn;
      }
      __syncthreads();
      // inp partials over own h-slice: partial[bb][tid] = Wain[tid, 16j..] . htl[bb]
      {
        float a0 = 0.0f, a1 = 0.0f;
        #pragma unroll
        for (int k = 0; k < 4; ++k) {
          const float4 w4 = *(const float4*)&waRow[k * 4];
          const float4 xa = *(const float4*)&htl_s[k * 4];
          const float4 xb = *(const float4*)&htl_s[16 + k * 4];
          DOT4(a0, w4, xa);
          DOT4(a1, w4, xb);
        }
        llc_storef(wsg + GQ_INPP + tid * 16 + j, a0);
        llc_storef(wsg + GQ_INPP + 4096 + tid * 16 + j, a1);
      }
    }
    group_barrier16(flags_g, j, tgt++);

    // ========== P2: inp gather, scores (2-pass fold), softmax stats, PV ==========
    {
      {
        const float* ib = wsg + GQ_INPP + bbj * 4096 + tid * 16;
        float4 a0, a1, a2, a3;
        llc_ld4x4(ib, ib + 4, ib + 8, ib + 12, a0, a1, a2, a3);
        const float s01 = ((a0.x + a0.y) + (a0.z + a0.w)) + ((a1.x + a1.y) + (a1.z + a1.w));
        const float s23 = ((a2.x + a2.y) + (a2.z + a2.w)) + ((a3.x + a3.y) + (a3.z + a3.w));
        inp_s[tid] = s01 + s23 + bain_s[tid];
      }
      __syncthreads();
      // scores: lane hq owns h-quad; 4 waves x 8 l's per pass, 2 passes
      {
        const float4 in4 = *(const float4*)&inp_s[hq * 4];
        const float4 v4  = *(const float4*)&V_s[hq * 4];
        #pragma unroll
        for (int pass = 0; pass < 2; ++pass) {
          const int lb = pass * 32 + lg * 8;
          float p0, p1, p2, p3, p4, p5, p6, p7;
          #define SCORE_P(dst, li)                                           \
            {                                                                \
              const float4 c4 = *(const float4*)&ctx[(lb + (li)) * CTX_LD + hq * 4]; \
              float p;                                                       \
              p = v4.x * fast_tanh(in4.x + c4.x);                            \
              p = fmaf(v4.y, fast_tanh(in4.y + c4.y), p);                    \
              p = fmaf(v4.z, fast_tanh(in4.z + c4.z), p);                    \
              p = fmaf(v4.w, fast_tanh(in4.w + c4.w), p);                    \
              dst = p;                                                       \
            }
          SCORE_P(p0, 0) SCORE_P(p1, 1) SCORE_P(p2, 2) SCORE_P(p3, 3)
          SCORE_P(p4, 4) SCORE_P(p5, 5) SCORE_P(p6, 6) SCORE_P(p7, 7)
          #undef SCORE_P
          // fold reduce: 10 shuffles (verified R9-R12)
          const bool hi32 = (hq & 32) != 0;
          float s, q0, q1, q2, q3, r0, r1, t0;
          s = hi32 ? p0 : p4; s = __shfl_xor(s, 32, 64); q0 = (hi32 ? p4 : p0) + s;
          s = hi32 ? p1 : p5; s = __shfl_xor(s, 32, 64); q1 = (hi32 ? p5 : p1) + s;
          s = hi32 ? p2 : p6; s = __shfl_xor(s, 32, 64); q2 = (hi32 ? p6 : p2) + s;
          s = hi32 ? p3 : p7; s = __shfl_xor(s, 32, 64); q3 = (hi32 ? p7 : p3) + s;
          const bool hi16 = (hq & 16) != 0;
          s = hi16 ? q0 : q2; s = __shfl_xor(s, 16, 64); r0 = (hi16 ? q2 : q0) + s;
          s = hi16 ? q1 : q3; s = __shfl_xor(s, 16, 64); r1 = (hi16 ? q3 : q1) + s;
          const bool hi8 = (hq & 8) != 0;
          s = hi8 ? r0 : r1; s = __shfl_xor(s, 8, 64); t0 = (hi8 ? r1 : r0) + s;
          t0 += __shfl_xor(t0, 4, 64);
          t0 += __shfl_xor(t0, 2, 64);
          t0 += __shfl_xor(t0, 1, 64);
          if ((hq & 7) == 0) {
            const int l = lb + ((hq >> 3) & 7);
            s_s[l] = (mask_s[l] == 0.0f) ? -INFINITY : t0;
          }
        }
      }
      __syncthreads();
      if (tid < 64) {   // single-wave softmax stats + candidate argmax
        const float sv = s_s[tid];
        const float e = expf(sv);          // masked -> exp(-inf)=0
        e_s[tid] = e;
        float ssum = e;
        #pragma unroll
        for (int m = 1; m < 64; m <<= 1) ssum += __shfl_xor(ssum, m, 64);
        float cv = sv; int ci = tid;
        #pragma unroll
        for (int m = 1; m < 64; m <<= 1) {
          const float ov = __shfl_xor(cv, m, 64);
          const int   oi = __shfl_xor(ci, m, 64);
          if (ov > cv || (ov == cv && oi < ci)) { cv = ov; ci = oi; }
        }
        if (tid == 0) {
          float* stb = wsg + GQ_STATS + (bbj * 8 + ck) * 4;
          llc_storef(stb + 0, ssum);
          llc_storef(stb + 1, cv);
          llc_storef(stb + 2, (float)(l0 + ci));
        }
      }
      __syncthreads();
      // PV: 16 l's per thread (both passes), partials scr[4][256]
      {
        float p0 = 0, p1 = 0, p2 = 0, p3 = 0;
        #pragma unroll
        for (int pass = 0; pass < 2; ++pass) {
          #pragma unroll
          for (int li = 0; li < 8; ++li) {
            const int l = pass * 32 + lg * 8 + li;
            const float ev = e_s[l];
            const float4 c4 = *(const float4*)&ctx[l * CTX_LD + hq * 4];
            p0 = fmaf(ev, c4.x, p0);
            p1 = fmaf(ev, c4.y, p1);
            p2 = fmaf(ev, c4.z, p2);
            p3 = fmaf(ev, c4.w, p3);
          }
        }
        __syncthreads();   // scr free (x staging consumed)
        *(float4*)&scr[lg * 256 + hq * 4] = make_float4(p0, p1, p2, p3);
      }
      __syncthreads();
      {
        float a = 0.0f;
        #pragma unroll
        for (int r2 = 0; r2 < 4; ++r2) a += scr[r2 * 256 + tid];
        llc_storef(wsg + GQ_ATT + (bbj * 8 + ck) * 256 + tid, a);
      }
    }
    group_barrier16(flags_g, j, tgt++);

    // ========== P3: gather stats+att+h_t (ONE drain), merge, alphas, u, Wo ==========
    {
      float4 sum4 = make_float4(0, 0, 0, 0), htv4 = make_float4(0, 0, 0, 0);
      if (tid >= 128 && tid < 144) {    // wave 2: stats gather (parallel drain)
        const float4 st = llc_ld4(wsg + GQ_STATS + (tid - 128) * 4);
        *(float4*)&stats_s[(tid - 128) * 4] = st;
      }
      if (tid < 128) {                  // waves 0-1: 8 att partials + h_t, ONE drain
        const int bbx = tid >> 6, h4 = tid & 63;
        const float* ab = wsg + GQ_ATT + bbx * 2048 + h4 * 4;
        float4 a0, a1, a2, a3, b0, b1, b2, b3;
        llc_ld9(ab, ab + 256, ab + 512, ab + 768, ab + 1024, ab + 1280,
                ab + 1536, ab + 1792, wsg + GQ_HT + bbx * 256 + h4 * 4,
                a0, a1, a2, a3, b0, b1, b2, b3, htv4);
        sum4.x = ((a0.x + a1.x) + (a2.x + a3.x)) + ((b0.x + b1.x) + (b2.x + b3.x));
        sum4.y = ((a0.y + a1.y) + (a2.y + a3.y)) + ((b0.y + b1.y) + (b2.y + b3.y));
        sum4.z = ((a0.z + a1.z) + (a2.z + a3.z)) + ((b0.z + b1.z) + (b2.z + b3.z));
        sum4.w = ((a0.w + a1.w) + (a2.w + a3.w)) + ((b0.w + b1.w) + (b2.w + b3.w));
      }
      __syncthreads();
      float Sb[2]; int wq[2];
      #pragma unroll
      for (int bb = 0; bb < 2; ++bb) {
        float Ssum = 0.0f;
        #pragma unroll
        for (int c2 = 0; c2 < 8; ++c2) Ssum += stats_s[(bb * 8 + c2) * 4];
        Sb[bb] = Ssum;
        float bv = stats_s[(bb * 8 + 0) * 4 + 1];
        int bI = (int)stats_s[(bb * 8 + 0) * 4 + 2];
        #pragma unroll
        for (int c2 = 1; c2 < 8; ++c2) {
          const float v2 = stats_s[(bb * 8 + c2) * 4 + 1];
          const int i2 = (int)stats_s[(bb * 8 + c2) * 4 + 2];
          if (v2 > bv || (v2 == bv && i2 < bI)) { bv = v2; bI = i2; }
        }
        wq[bb] = bI;
      }
      const float Sown = (bbj == 0) ? Sb[0] : Sb[1];
      const int wown = (bbj == 0) ? wq[0] : wq[1];
      if (tid < 16) {
        const float4 e4 = *(const float4*)&e_s[tid * 4];
        *(float4*)&out[(size_t)b_ctx * Ln * Ln + (size_t)t * Ln + l0 + tid * 4] =
            make_float4(e4.x / Sown, e4.y / Sown, e4.z / Sown, e4.w / Sown);
      }
      if (tid == 0) {
        if (wown >= l0 && wown < l0 + 64) mask_s[wown - l0] = 0.0f;
        if (ck == 0) out[PTR_OFF + (size_t)b_ctx * Ln + t] = (float)wown;
      }
      // u staging: scr[bb][520] = [att_sum/S ; h_t]
      if (tid < 128) {
        const int bbx = tid >> 6, h4 = tid & 63;
        const float Sx = (bbx == 0) ? Sb[0] : Sb[1];
        *(float4*)&scr[bbx * UPAD + h4 * 4] =
            make_float4(sum4.x / Sx, sum4.y / Sx, sum4.z / Sx, sum4.w / Sx);
        *(float4*)&scr[bbx * UPAD + 256 + h4 * 4] = htv4;
      }
      __syncthreads();
      // Wo rows (L2-streamed, load-once-use-twice)
      {
        float a0 = 0.0f, a1 = 0.0f;
        #pragma unroll
        for (int k = 0; k < 8; ++k) {
          const float4 w4 = *(const float4*)&woRow[k * 64 + seg16 * 4];
          const float4 xa = *(const float4*)&scr[k * 64 + seg16 * 4];
          const float4 xb = *(const float4*)&scr[UPAD + k * 64 + seg16 * 4];
          DOT4(a0, w4, xa);
          DOT4(a1, w4, xb);
        }
        a0 += __shfl_xor(a0, 1, 64);
        a0 += __shfl_xor(a0, 2, 64);
        a0 += __shfl_xor(a0, 4, 64);
        a0 += __shfl_xor(a0, 8, 64);
        a1 += __shfl_xor(a1, 1, 64);
        a1 += __shfl_xor(a1, 2, 64);
        a1 += __shfl_xor(a1, 4, 64);
        a1 += __shfl_xor(a1, 8, 64);
        if (seg16 == 0) {
          const float hv0 = tanhf(a0 + bo_r);
          const float hv1 = tanhf(a1 + bo_r);
          llc_storef(wsg + GQ_HID + r16, hv0);
          llc_storef(wsg + GQ_HID + 256 + r16, hv1);
          if (t == Tn - 1) {
            out[HF_OFF + (size_t)(gq * 2 + 0) * Hn + r16] = hv0;
            out[HF_OFF + (size_t)(gq * 2 + 1) * Hn + r16] = hv1;
          }
        }
      }
      w0 = wq[0]; w1 = wq[1];
    }
    group_barrier16(flags_g, j, tgt++);
  }
}

extern "C" void kernel_launch(void* const* d_in, const int* in_sizes, int n_in,
                              void* d_out, int out_size, void* d_ws, size_t ws_size,
                              hipStream_t stream) {
  (void)in_sizes; (void)n_in; (void)out_size; (void)ws_size;
  (void)hipFuncSetAttribute(reinterpret_cast<const void*>(decoder_main),
                            hipFuncAttributeMaxDynamicSharedMemorySize, SMEM_FL * 4);
  (void)hipMemsetAsync(d_ws, 0, 65536, stream);   // zero barrier flags each launch/replay

  const float* emb   = (const float*)d_in[0];
  const float* dec0  = (const float*)d_in[1];
  const float* h0    = (const float*)d_in[2];
  const float* c0    = (const float*)d_in[3];
  const float* ctxg  = (const float*)d_in[4];
  const float* Wi    = (const float*)d_in[5];
  const float* bi    = (const float*)d_in[6];
  const float* Wh    = (const float*)d_in[7];
  const float* bh    = (const float*)d_in[8];
  const float* Wo    = (const float*)d_in[9];
  const float* bo    = (const float*)d_in[10];
  const float* Wain  = (const float*)d_in[11];
  const float* bain  = (const float*)d_in[12];
  const float* Wactx = (const float*)d_in[13];
  const float* bactx = (const float*)d_in[14];
  const float* V     = (const float*)d_in[15];

  unsigned* flags = (unsigned*)d_ws;
  float* wsd = (float*)((char*)d_ws + 65536);

  decoder_main<<<NBLK, NTHR, SMEM_FL * 4, stream>>>(
      emb, dec0, h0, c0, ctxg, Wi, bi, Wh, bh, Wo, bo, Wain, bain, Wactx, bactx, V,
      (float*)d_out, flags, wsd);
}

// Round 15
// 10655.656 us; speedup vs baseline: 2.0770x; 1.0738x over previous
//
#include <hip/hip_runtime.h>
#include <math.h>

#define SCOPE __HIP_MEMORY_SCOPE_AGENT

constexpr int Bn = 64, Ln = 512, En = 128, Hn = 256, Tn = 512;
constexpr int NBLK = 256, NTHR = 512;
constexpr int CTX_LD = 260, HTPAD = 264, XPAD = 384, UPAD = 520;

// ---- LDS layout (floats) ----
constexpr int OFF_CTX = 0;                   // [128][260] ctx slice
constexpr int OFF_SCR = 128 * CTX_LD;        // 4096: init stage / x / PV partials / u
constexpr int OFF_HT  = OFF_SCR + 4096;      // h_t [4][264]
constexpr int OFF_INP = OFF_HT + 4 * HTPAD;  // inp (own batch) [256]
constexpr int OFF_SS  = OFF_INP + 256;       // scores [128]
constexpr int OFF_ES  = OFF_SS + 128;        // e [128]
constexpr int OFF_MK  = OFF_ES + 128;        // mask [128]
constexpr int OFF_VS  = OFF_MK + 128;        // V [256]
constexpr int OFF_GS  = OFF_VS + 256;        // gate pre-activations [4bb][4g][16h]
constexpr int OFF_ST  = OFF_GS + 256;        // stats [16][4]
constexpr int OFF_WR  = OFF_ST + 64;         // reduce scratch [64]
constexpr int OFF_BA  = OFF_WR + 64;         // bain [256]
constexpr int OFF_HTL = OFF_BA + 256;        // own-slice h_t [4][16]
constexpr int SMEM_FL = OFF_HTL + 64;        // 40032 floats = 160128 B (<= 160 KiB)

// ---- output layout ----
constexpr size_t PTR_OFF = (size_t)Bn * Ln * Ln;
constexpr size_t HF_OFF  = PTR_OFF + (size_t)Bn * Ln;
constexpr size_t CF_OFF  = HF_OFF + (size_t)Bn * Hn;

// ---- ws: [0,32KB) flags (16 groups x 16 x 32 uints); then per-group floats ----
constexpr int GQ_HT    = 0;      // h_t [4][256]
constexpr int GQ_HID   = 1024;   // hidden [4][256]
constexpr int GQ_ATT   = 2048;   // att partials [4bb*4ck][256]
constexpr int GQ_STATS = 6144;   // [16][4] {S, candv, candi, pad}
constexpr int GQ_INPP  = 6208;   // inp partials [4bb][256g][16j]
constexpr int GQ_STRIDE = 6208 + 16384;

__device__ __forceinline__ float fast_tanh(float x) {
  const float e = __expf(2.0f * x);
  return 1.0f - __fdividef(2.0f, 1.0f + e);
}
__device__ __forceinline__ float sigmoidf_(float x) {
  return 1.0f / (1.0f + expf(-x));
}
// relaxed agent-scope (LLC) scalar accessors (sc0|sc1, no cache invalidation)
__device__ __forceinline__ void llc_storef(float* p, float v) {
  __hip_atomic_store(p, v, __ATOMIC_RELAXED, SCOPE);
}
// vectorized LLC loads via explicit sc0|sc1 flags (float4 asm OUTPUTS ok; no asm stores)
__device__ __forceinline__ float4 llc_ld4(const float* p) {
  float4 r;
  asm volatile("global_load_dwordx4 %0, %1, off sc0 sc1\n\ts_waitcnt vmcnt(0)"
               : "=&v"(r) : "v"(p) : "memory");
  return r;
}
__device__ __forceinline__ void llc_ld4x4(const float* p0, const float* p1,
                                          const float* p2, const float* p3,
                                          float4& a, float4& b, float4& c, float4& d) {
  asm volatile(
      "global_load_dwordx4 %0, %4, off sc0 sc1\n\t"
      "global_load_dwordx4 %1, %5, off sc0 sc1\n\t"
      "global_load_dwordx4 %2, %6, off sc0 sc1\n\t"
      "global_load_dwordx4 %3, %7, off sc0 sc1\n\t"
      "s_waitcnt vmcnt(0)"
      : "=&v"(a), "=&v"(b), "=&v"(c), "=&v"(d)
      : "v"(p0), "v"(p1), "v"(p2), "v"(p3) : "memory");
}
// 5 loads, ONE drain (P2 gather: 4 inp-partial chunks + h_t) — single serial trip
__device__ __forceinline__ void llc_ld5(const float* p0, const float* p1,
                                        const float* p2, const float* p3,
                                        const float* p4,
                                        float4& a, float4& b, float4& c,
                                        float4& d, float4& e) {
  asm volatile(
      "global_load_dwordx4 %0, %5, off sc0 sc1\n\t"
      "global_load_dwordx4 %1, %6, off sc0 sc1\n\t"
      "global_load_dwordx4 %2, %7, off sc0 sc1\n\t"
      "global_load_dwordx4 %3, %8, off sc0 sc1\n\t"
      "global_load_dwordx4 %4, %9, off sc0 sc1\n\t"
      "s_waitcnt vmcnt(0)"
      : "=&v"(a), "=&v"(b), "=&v"(c), "=&v"(d), "=&v"(e)
      : "v"(p0), "v"(p1), "v"(p2), "v"(p3), "v"(p4) : "memory");
}

// 16-block group barrier: relaxed LLC flags; vmcnt(0) drained before flag store
__device__ __forceinline__ void group_barrier16(unsigned* flags_g, int j, unsigned tgt) {
  asm volatile("s_waitcnt vmcnt(0)" ::: "memory");
  __syncthreads();
  if (threadIdx.x == 0)
    __hip_atomic_store(&flags_g[j * 32], tgt, __ATOMIC_RELAXED, SCOPE);
  if (threadIdx.x < 16) {
    long spins = 0;
    while (__hip_atomic_load(&flags_g[threadIdx.x * 32], __ATOMIC_RELAXED, SCOPE) < tgt) {
      __builtin_amdgcn_s_sleep(1);
      if (++spins > 50000000L) __builtin_trap();
    }
  }
  __syncthreads();
  asm volatile("" ::: "memory");
}

#define DOT4(acc, w4, x4) \
  acc = fmaf((w4).x, (x4).x, fmaf((w4).y, (x4).y, fmaf((w4).z, (x4).z, fmaf((w4).w, (x4).w, (acc)))))

__global__ void __launch_bounds__(NTHR, 1)
decoder_main(const float* __restrict__ emb, const float* __restrict__ dec0,
             const float* __restrict__ h0,  const float* __restrict__ c0,
             const float* __restrict__ ctxg,const float* __restrict__ Wi,
             const float* __restrict__ bi,  const float* __restrict__ Wh,
             const float* __restrict__ bh,  const float* __restrict__ Wo,
             const float* __restrict__ bo,  const float* __restrict__ Wain,
             const float* __restrict__ bain,const float* __restrict__ Wactx,
             const float* __restrict__ bactx,const float* __restrict__ Vv,
             float* __restrict__ out, unsigned* __restrict__ flags,
             float* __restrict__ wsd)
{
  extern __shared__ float sm[];
  float* ctx    = sm + OFF_CTX;
  float* scr    = sm + OFF_SCR;
  float* x_s    = sm + OFF_SCR;     // alias (phase P1)
  float* h_t_s  = sm + OFF_HT;
  float* inp_s  = sm + OFF_INP;
  float* s_s    = sm + OFF_SS;
  float* e_s    = sm + OFF_ES;
  float* mask_s = sm + OFF_MK;
  float* V_s    = sm + OFF_VS;
  float* gsum   = sm + OFF_GS;
  float* stats_s= sm + OFF_ST;
  float* wred   = sm + OFF_WR;
  float* bain_s = sm + OFF_BA;
  float* htl_s  = sm + OFF_HTL;
  int*   wredi  = (int*)wred;

  const int tid = threadIdx.x, bid = blockIdx.x;
  const int gq = bid >> 4, j = bid & 15;
  const int bbj = j >> 2, ck = j & 3;
  const int b_ctx = gq * 4 + bbj;
  const int l0 = ck * 128;

  // role indices
  const int team = tid >> 3, seg8 = tid & 7;       // gates: 8 thr/row, 64 rows
  const int gteam = team >> 4, hloc = team & 15;
  const int r_abs = gteam * 256 + j * 16 + hloc;   // gate row (g, h=j*16+hloc)
  const int g2 = tid >> 1, half = tid & 1;         // inp partial: 2 thr/row
  const int r16loc = tid >> 5, seg32 = tid & 31;   // Wo: 32 thr/row, 16 rows
  const int r16 = j * 16 + r16loc;

  unsigned* flags_g = flags + gq * (16 * 32);
  float* wsg = wsd + (size_t)gq * GQ_STRIDE;

  // ---- register-resident weights (72 floats/thread total: proven budget) ----
  float4 wg4[12];
  #pragma unroll
  for (int k = 0; k < 4; ++k) wg4[k] = *(const float4*)&Wi[(size_t)r_abs * En + k * 32 + seg8 * 4];
  #pragma unroll
  for (int k = 0; k < 8; ++k) wg4[4 + k] = *(const float4*)&Wh[(size_t)r_abs * Hn + k * 32 + seg8 * 4];
  const float bias_g = bi[r_abs] + bh[r_abs];

  float4 wa4[2];   // Wain[g2][j*16 + half*8 .. +8]  (column slice of own h-block)
  #pragma unroll
  for (int k = 0; k < 2; ++k)
    wa4[k] = *(const float4*)&Wain[(size_t)g2 * Hn + j * 16 + half * 8 + k * 4];

  float4 wo4[4];
  #pragma unroll
  for (int k = 0; k < 4; ++k) wo4[k] = *(const float4*)&Wo[(size_t)r16 * (2 * Hn) + k * 128 + seg32 * 4];
  const float bo_r = bo[r16];

  // cell state: tid<64 owns (bb=tid>>4, h=j*16+(tid&15))
  float cst = 0.0f;
  if (tid < 64) cst = c0[(size_t)(gq * 4 + (tid >> 4)) * Hn + j * 16 + (tid & 15)];

  if (tid < 128) mask_s[tid] = 1.0f;
  if (tid < 256) { V_s[tid] = Vv[tid]; bain_s[tid] = bain[tid]; }

  // ---- one-time ctx_proj slice into LDS (batch b_ctx, l in [l0,l0+128)) ----
  {
    const int gc = tid & 31;
    const int lg = tid >> 5;
    float acc[8][8];
    #pragma unroll
    for (int a2 = 0; a2 < 8; ++a2)
      #pragma unroll
      for (int b2 = 0; b2 < 8; ++b2) acc[a2][b2] = 0.0f;
    float* stg_c = scr;
    float* stg_w = scr + 1024;
    for (int kc = 0; kc < 32; ++kc) {
      __syncthreads();
      for (int i = tid; i < 1024; i += NTHR) {
        int k = i & 7, l = i >> 3;
        stg_c[k * 128 + l] = ctxg[((size_t)(b_ctx * Ln + l0 + l)) * Hn + kc * 8 + k];
      }
      for (int i = tid; i < 2048; i += NTHR) {
        int k = i & 7, gg = i >> 3;
        stg_w[k * 256 + gg] = Wactx[(size_t)gg * Hn + kc * 8 + k];
      }
      __syncthreads();
      #pragma unroll
      for (int kk = 0; kk < 8; ++kk) {
        float cl[8], wgt[8];
        #pragma unroll
        for (int jj = 0; jj < 8; ++jj) cl[jj] = stg_c[kk * 128 + lg * 8 + jj];
        #pragma unroll
        for (int jj = 0; jj < 8; ++jj) wgt[jj] = stg_w[kk * 256 + gc * 8 + jj];
        #pragma unroll
        for (int li = 0; li < 8; ++li)
          #pragma unroll
          for (int gi = 0; gi < 8; ++gi)
            acc[li][gi] = fmaf(cl[li], wgt[gi], acc[li][gi]);
      }
    }
    __syncthreads();
    #pragma unroll
    for (int li = 0; li < 8; ++li)
      #pragma unroll
      for (int gi = 0; gi < 8; ++gi)
        ctx[(lg * 8 + li) * CTX_LD + gc * 8 + gi] = acc[li][gi] + bactx[gc * 8 + gi];
  }
  __syncthreads();

  unsigned tgt = 1;
  int w0 = 0, w1 = 0, w2 = 0, w3 = 0;

  for (int t = 0; t < Tn; ++t) {
    // ========== P1: x stage, gates GEMV, local cell, h_t + inp-partial publish ==========
    {
      if (tid < 256) {           // hidden/h0 -> x[bb][128..384]
        const int bbx = tid >> 6, h4 = tid & 63;
        float4 v;
        if (t == 0) v = *(const float4*)&h0[(size_t)(gq * 4 + bbx) * Hn + h4 * 4];
        else        v = llc_ld4(wsg + GQ_HID + bbx * 256 + h4 * 4);
        *(float4*)&x_s[bbx * XPAD + 128 + h4 * 4] = v;
      } else if (tid < 384) {    // emb/dec0 -> x[bb][0..128]
        const int i2 = tid - 256, bbx = i2 >> 5, k4 = i2 & 31;
        const int gb = gq * 4 + bbx;
        float4 v;
        if (t == 0) v = *(const float4*)&dec0[(size_t)gb * En + k4 * 4];
        else {
          const int wsel = (bbx == 0) ? w0 : (bbx == 1) ? w1 : (bbx == 2) ? w2 : w3;
          v = *(const float4*)&emb[((size_t)gb * Ln + wsel) * En + k4 * 4];
        }
        *(float4*)&x_s[bbx * XPAD + k4 * 4] = v;
      }
      __syncthreads();
      #pragma unroll
      for (int bb = 0; bb < 4; ++bb) {
        float acc = 0.0f;
        #pragma unroll
        for (int k = 0; k < 12; ++k) {
          const float4 x4 = *(const float4*)&x_s[bb * XPAD + k * 32 + seg8 * 4];
          DOT4(acc, wg4[k], x4);
        }
        acc += __shfl_xor(acc, 1, 64);
        acc += __shfl_xor(acc, 2, 64);
        acc += __shfl_xor(acc, 4, 64);
        if (seg8 == 0) gsum[bb * 64 + team] = acc + bias_g;   // [bb][g*16+h]
      }
      __syncthreads();
      if (tid < 64) {
        const int bbx = tid >> 4, hx = tid & 15;
        const float iv = gsum[bbx * 64 + hx];
        const float fv = gsum[bbx * 64 + 16 + hx];
        const float gv = gsum[bbx * 64 + 32 + hx];
        const float ov = gsum[bbx * 64 + 48 + hx];
        const float cn = sigmoidf_(fv) * cst + sigmoidf_(iv) * tanhf(gv);
        const float htv = sigmoidf_(ov) * tanhf(cn);
        cst = cn;
        htl_s[bbx * 16 + hx] = htv;
        llc_storef(wsg + GQ_HT + bbx * 256 + j * 16 + hx, htv);
        if (t == Tn - 1) out[CF_OFF + (size_t)(gq * 4 + bbx) * Hn + j * 16 + hx] = cn;
      }
      __syncthreads();
      // inp partials over own h-slice: partial[bb][g2] = Wain[g2, 16j..] . htl[bb]
      {
        float pac[4];
        #pragma unroll
        for (int bb = 0; bb < 4; ++bb) {
          float acc = 0.0f;
          #pragma unroll
          for (int k = 0; k < 2; ++k) {
            const float4 x4 = *(const float4*)&htl_s[bb * 16 + half * 8 + k * 4];
            DOT4(acc, wa4[k], x4);
          }
          pac[bb] = acc;
        }
        #pragma unroll
        for (int bb = 0; bb < 4; ++bb) {
          const float o = __shfl_xor(pac[bb], 1, 64);
          pac[bb] += o;
        }
        if (half == 0) {
          #pragma unroll
          for (int bb = 0; bb < 4; ++bb)
            llc_storef(wsg + GQ_INPP + bb * 4096 + g2 * 16 + j, pac[bb]);
        }
      }
    }
    group_barrier16(flags_g, j, tgt++);

    // ========== P2: gather h_t + inp partials (ONE drain), scores, softmax, PV ==========
    {
      if (tid < 256) {
        const int bbx = tid >> 6, h4 = tid & 63;
        const float* ib = wsg + GQ_INPP + bbj * 4096 + tid * 16;
        float4 a0, a1, a2, a3, hv;
        llc_ld5(ib, ib + 4, ib + 8, ib + 12, wsg + GQ_HT + tid * 4,
                a0, a1, a2, a3, hv);
        *(float4*)&h_t_s[bbx * HTPAD + h4 * 4] = hv;
        const float s01 = ((a0.x + a0.y) + (a0.z + a0.w)) + ((a1.x + a1.y) + (a1.z + a1.w));
        const float s23 = ((a2.x + a2.y) + (a2.z + a2.w)) + ((a3.x + a3.y) + (a3.z + a3.w));
        inp_s[tid] = s01 + s23 + bain_s[tid];
      }
      __syncthreads();
      {
        const int l = tid >> 2, q = tid & 3;
        float p = 0.0f;
        #pragma unroll
        for (int i = 0; i < 16; ++i) {
          const int h4 = q * 64 + i * 4;
          const float4 c4 = *(const float4*)&ctx[l * CTX_LD + h4];
          const float4 in4 = *(const float4*)&inp_s[h4];
          const float4 v4 = *(const float4*)&V_s[h4];
          p = fmaf(v4.x, fast_tanh(in4.x + c4.x), p);
          p = fmaf(v4.y, fast_tanh(in4.y + c4.y), p);
          p = fmaf(v4.z, fast_tanh(in4.z + c4.z), p);
          p = fmaf(v4.w, fast_tanh(in4.w + c4.w), p);
        }
        p += __shfl_xor(p, 1, 64);
        p += __shfl_xor(p, 2, 64);
        if (q == 0) s_s[l] = (mask_s[l] == 0.0f) ? -INFINITY : p;
      }
      __syncthreads();
      if (tid < 128) {
        const float sv = s_s[tid];
        const float e = expf(sv);         // no max-sub: |s| <= sum|V| ~ 10, safe in fp32
        e_s[tid] = e;
        float ssum = e;
        #pragma unroll
        for (int m = 1; m < 64; m <<= 1) ssum += __shfl_xor(ssum, m, 64);
        float cv = sv; int ci = tid;
        #pragma unroll
        for (int m = 1; m < 64; m <<= 1) {
          const float ov = __shfl_xor(cv, m, 64);
          const int   oi = __shfl_xor(ci, m, 64);
          if (ov > cv || (ov == cv && oi < ci)) { cv = ov; ci = oi; }
        }
        if ((tid & 63) == 0) {
          wred[tid >> 6] = ssum;
          wred[4 + (tid >> 6)] = cv;
          wredi[8 + (tid >> 6)] = ci;
        }
      }
      __syncthreads();
      if (tid == 0) {
        const float S = wred[0] + wred[1];
        float bv = wred[4]; int bI = wredi[8];
        if (wred[5] > bv || (wred[5] == bv && wredi[9] < bI)) { bv = wred[5]; bI = wredi[9]; }
        float* stb = wsg + GQ_STATS + (bbj * 4 + ck) * 4;
        llc_storef(stb + 0, S);
        llc_storef(stb + 1, bv);
        llc_storef(stb + 2, (float)(l0 + bI));
      }
      {
        const int h4g = tid & 63, lgq = tid >> 6;
        float p0 = 0, p1 = 0, p2 = 0, p3 = 0;
        #pragma unroll
        for (int li = 0; li < 16; ++li) {
          const int l = lgq * 16 + li;
          const float ev = e_s[l];
          const float4 c4 = *(const float4*)&ctx[l * CTX_LD + h4g * 4];
          p0 = fmaf(ev, c4.x, p0);
          p1 = fmaf(ev, c4.y, p1);
          p2 = fmaf(ev, c4.z, p2);
          p3 = fmaf(ev, c4.w, p3);
        }
        *(float4*)&scr[lgq * 256 + h4g * 4] = make_float4(p0, p1, p2, p3);
      }
      __syncthreads();
      if (tid < 256) {
        float a = 0.0f;
        #pragma unroll
        for (int r2 = 0; r2 < 8; ++r2) a += scr[r2 * 256 + tid];
        llc_storef(wsg + GQ_ATT + (bbj * 4 + ck) * 256 + tid, a);
      }
    }
    group_barrier16(flags_g, j, tgt++);

    // ========== P3: merge stats, alphas, pointer, mask, u, Wo rows, hidden ==========
    {
      if (tid >= 256 && tid < 272) {    // wave 4: stats gather (parallel drain)
        const float4 st = llc_ld4(wsg + GQ_STATS + (tid - 256) * 4);
        *(float4*)&stats_s[(tid - 256) * 4] = st;
      }
      float4 a0, a1, a2, a3;
      if (tid < 256) {                  // waves 0-3: att partials, one drain
        const int h4 = tid & 63;
        const int bbx = tid >> 6;
        const float* ab = wsg + GQ_ATT + bbx * 4 * 256 + h4 * 4;
        llc_ld4x4(ab, ab + 256, ab + 512, ab + 768, a0, a1, a2, a3);
      }
      __syncthreads();
      float Sb[4]; int wq[4];
      #pragma unroll
      for (int bb = 0; bb < 4; ++bb) {
        Sb[bb] = ((stats_s[(bb * 4 + 0) * 4] + stats_s[(bb * 4 + 1) * 4])
                  + stats_s[(bb * 4 + 2) * 4]) + stats_s[(bb * 4 + 3) * 4];
        float bv = stats_s[(bb * 4 + 0) * 4 + 1];
        int bI = (int)stats_s[(bb * 4 + 0) * 4 + 2];
        #pragma unroll
        for (int c2 = 1; c2 < 4; ++c2) {
          const float v2 = stats_s[(bb * 4 + c2) * 4 + 1];
          const int i2 = (int)stats_s[(bb * 4 + c2) * 4 + 2];
          if (v2 > bv || (v2 == bv && i2 < bI)) { bv = v2; bI = i2; }
        }
        wq[bb] = bI;
      }
      const float Sown = (bbj == 0) ? Sb[0] : (bbj == 1) ? Sb[1] : (bbj == 2) ? Sb[2] : Sb[3];
      const int wown = (bbj == 0) ? wq[0] : (bbj == 1) ? wq[1] : (bbj == 2) ? wq[2] : wq[3];
      if (tid < 32) {
        const float4 e4 = *(const float4*)&e_s[tid * 4];
        *(float4*)&out[(size_t)b_ctx * Ln * Ln + (size_t)t * Ln + l0 + tid * 4] =
            make_float4(e4.x / Sown, e4.y / Sown, e4.z / Sown, e4.w / Sown);
      }
      if (tid == 0) {
        if (wown >= l0 && wown < l0 + 128) mask_s[wown - l0] = 0.0f;
        if (ck == 0) out[PTR_OFF + (size_t)b_ctx * Ln + t] = (float)wown;
      }
      // u staging: scr[bb][520] = [att_sum/S ; h_t]
      if (tid < 256) {
        const int bbx = tid >> 6, h4 = tid & 63;
        const float Sx = (bbx == 0) ? Sb[0] : (bbx == 1) ? Sb[1] : (bbx == 2) ? Sb[2] : Sb[3];
        float4 u4;
        u4.x = (((a0.x + a1.x) + a2.x) + a3.x) / Sx;
        u4.y = (((a0.y + a1.y) + a2.y) + a3.y) / Sx;
        u4.z = (((a0.z + a1.z) + a2.z) + a3.z) / Sx;
        u4.w = (((a0.w + a1.w) + a2.w) + a3.w) / Sx;
        *(float4*)&scr[bbx * UPAD + h4 * 4] = u4;
      } else {
        const int i2 = tid - 256, bbx = i2 >> 6, h4 = i2 & 63;
        const float4 hv = *(const float4*)&h_t_s[bbx * HTPAD + h4 * 4];
        *(float4*)&scr[bbx * UPAD + 256 + h4 * 4] = hv;
      }
      __syncthreads();
      #pragma unroll
      for (int bb = 0; bb < 4; ++bb) {
        float acc = 0.0f;
        #pragma unroll
        for (int k = 0; k < 4; ++k) {
          const float4 x4 = *(const float4*)&scr[bb * UPAD + k * 128 + seg32 * 4];
          DOT4(acc, wo4[k], x4);
        }
        acc += __shfl_xor(acc, 1, 64);
        acc += __shfl_xor(acc, 2, 64);
        acc += __shfl_xor(acc, 4, 64);
        acc += __shfl_xor(acc, 8, 64);
        acc += __shfl_xor(acc, 16, 64);
        if (seg32 == 0) {
          const float hv = tanhf(acc + bo_r);
          llc_storef(wsg + GQ_HID + bb * 256 + r16, hv);
          if (t == Tn - 1) out[HF_OFF + (size_t)(gq * 4 + bb) * Hn + r16] = hv;
        }
      }
      w0 = wq[0]; w1 = wq[1]; w2 = wq[2]; w3 = wq[3];
    }
    group_barrier16(flags_g, j, tgt++);
  }
}

extern "C" void kernel_launch(void* const* d_in, const int* in_sizes, int n_in,
                              void* d_out, int out_size, void* d_ws, size_t ws_size,
                              hipStream_t stream) {
  (void)in_sizes; (void)n_in; (void)out_size; (void)ws_size;
  (void)hipFuncSetAttribute(reinterpret_cast<const void*>(decoder_main),
                            hipFuncAttributeMaxDynamicSharedMemorySize, SMEM_FL * 4);
  (void)hipMemsetAsync(d_ws, 0, 32768, stream);   // zero barrier flags each launch/replay

  const float* emb   = (const float*)d_in[0];
  const float* dec0  = (const float*)d_in[1];
  const float* h0    = (const float*)d_in[2];
  const float* c0    = (const float*)d_in[3];
  const float* ctxg  = (const float*)d_in[4];
  const float* Wi    = (const float*)d_in[5];
  const float* bi    = (const float*)d_in[6];
  const float* Wh    = (const float*)d_in[7];
  const float* bh    = (const float*)d_in[8];
  const float* Wo    = (const float*)d_in[9];
  const float* bo    = (const float*)d_in[10];
  const float* Wain  = (const float*)d_in[11];
  const float* bain  = (const float*)d_in[12];
  const float* Wactx = (const float*)d_in[13];
  const float* bactx = (const float*)d_in[14];
  const float* V     = (const float*)d_in[15];

  unsigned* flags = (unsigned*)d_ws;
  float* wsd = (float*)((char*)d_ws + 32768);

  decoder_main<<<NBLK, NTHR, SMEM_FL * 4, stream>>>(
      emb, dec0, h0, c0, ctxg, Wi, bi, Wh, bh, Wo, bo, Wain, bain, Wactx, bactx, V,
      (float*)d_out, flags, wsd);
}